// Round 10
// baseline (372.352 us; speedup 1.0000x reference)
//
#include <hip/hip_runtime.h>
#include <hip/hip_bf16.h>
#include <stdint.h>
#include <stddef.h>

typedef __bf16 bf16_t;
typedef __attribute__((ext_vector_type(8))) __bf16 bf16x8;
typedef __attribute__((ext_vector_type(4))) __bf16 bf16x4;
typedef __attribute__((ext_vector_type(4))) float f32x4;
typedef __attribute__((ext_vector_type(4))) int i32x4;

#define M_DIM 32768
#define N_DIM 4096
#define K_DIM 1024
#define NT 32  // K / 32

static __device__ __forceinline__ void gload16(const void* g, void* s) {
  __builtin_amdgcn_global_load_lds(
      (const __attribute__((address_space(1))) void*)g,
      (__attribute__((address_space(3))) void*)s,
      16, 0, 0);
}

// ---------------- x: fp32 [M][K] -> bf16 [M][K] ----------------
__global__ void cvt_x_kernel(const float* __restrict__ x, bf16_t* __restrict__ xb) {
  const long n8 = (long)M_DIM * K_DIM / 8;
  long i = (long)blockIdx.x * blockDim.x + threadIdx.x;
  const long stride = (long)gridDim.x * blockDim.x;
  for (; i < n8; i += stride) {
    const float4* p = (const float4*)(x + i * 8);
    float4 v0 = p[0];
    float4 v1 = p[1];
    bf16x8 o;
    o[0] = (__bf16)v0.x; o[1] = (__bf16)v0.y; o[2] = (__bf16)v0.z; o[3] = (__bf16)v0.w;
    o[4] = (__bf16)v1.x; o[5] = (__bf16)v1.y; o[6] = (__bf16)v1.z; o[7] = (__bf16)v1.w;
    *(bf16x8*)(xb + i * 8) = o;
  }
}

// ---------------- w: int32 [K][N] -> bf16 Wt [N][K] (exact) ----------------
__global__ void cvt_w_kernel(const int* __restrict__ qw, bf16_t* __restrict__ wt) {
  __shared__ bf16_t t[64][72];
  const int bk = blockIdx.x & 15;
  const int bn = blockIdx.x >> 4;
  const int k0 = bk * 64, n0 = bn * 64;
  const int tid = threadIdx.x;
  {
    const int kl = tid >> 2;
    const int nc = (tid & 3) * 16;
    const int* src = qw + (long)(k0 + kl) * N_DIM + n0 + nc;
#pragma unroll
    for (int c = 0; c < 4; ++c) {
      i32x4 v = *(const i32x4*)(src + c * 4);
#pragma unroll
      for (int j = 0; j < 4; ++j)
        t[nc + c * 4 + j][kl] = (bf16_t)(float)v[j];
    }
  }
  __syncthreads();
  {
    const int nl = tid >> 2;
    const int kc = (tid & 3) * 16;
    bf16_t* dst = wt + (long)(n0 + nl) * K_DIM + k0 + kc;
#pragma unroll
    for (int j = 0; j < 16; ++j) dst[j] = t[nl][kc + j];
  }
}

// ---------------- GEMM 128x128, BK=32, 4 waves, 4 blocks/CU --------------
// LDS = 2 bufs x 16KB (A 8KB [128 slots][64B] + B 8KB) = 32KB -> 4 blocks/CU
// (round-9 binary was 108 VGPR, so 4 waves/SIMD fits the 128-VGPR budget).
// BK=32 rows are 64B: every frag-read wave footprint is a contiguous 1KB
// block -> bank-conflict-free WITHOUT any swizzle; staging stays linear.
// Each wave reads only A[wm-half] and B[wn-half] of the staged issues.
// Per tile: ONE sync point {vmcnt(0); s_barrier} is sufficient:
//   RAW: own staged loads done (vmcnt) + barrier extends to all waves' DMA.
//   WAR: all reads of tile t-1 (buffer nb) precede the barrier in program
//        order; stages into nb follow it.
// In-flight at the sync = exactly tile t's 4 issues (nothing for t+1 yet),
// so vmcnt(0) does not over-drain; 4-way block overlap hides the wait.
__global__ __launch_bounds__(256, 4) void gemm128_kernel(
    const bf16_t* __restrict__ A, const bf16_t* __restrict__ Bt,
    const float* __restrict__ scale_p, const float* __restrict__ bias,
    float* __restrict__ C) {
  __shared__ __align__(16) char lds[32768];

  // XCD ownership (bijective; nwg = 8192): XCD x owns tn {4x..4x+3}; tnl
  // iterates fastest so consecutive blocks share one A-tile; all XCDs sweep
  // the same tm window concurrently (A served via LLC, ~8MB window).
  const int xcd = blockIdx.x & 7;
  const int slot = blockIdx.x >> 3;        // 0..1023
  const int tn = (xcd << 2) | (slot & 3);  // 0..31
  const int tm = slot >> 2;                // 0..255

  const int tid = threadIdx.x;
  const int wave = tid >> 6;  // 0..3
  const int lane = tid & 63;
  const int lr = lane & 15;
  const int lg = lane >> 4;
  const int wm = wave >> 1;  // 0..1
  const int wn = wave & 1;   // 0..1

  const long aRow0 = (long)tm * 128;
  const long bRow0 = (long)tn * 128;

  // staging: issue = 4KB = 64 slots x 64B; wave w writes slots w*16..w*16+15
  // (1KB, lane*16 linear). Thread covers slot srow = w*16 + lane/4,
  // chunk lane&3 (16B). No swizzle.
  const int srow = wave * 16 + (lane >> 2);
  const int scol = (lane & 3) * 8;
  const bf16_t* aS = A + (aRow0 + srow) * K_DIM + scol;
  const bf16_t* bS = Bt + (bRow0 + srow) * K_DIM + scol;
  char* sBase = lds + wave * 1024;

  // buf b: A at b*16384 (slot sigma=row, byte sigma*64), B at b*16384+8192.
#define STG_A(b, h, t)                                                \
  gload16(aS + (long)((h) * 64) * K_DIM + (t) * 32,                   \
          sBase + (b) * 16384 + (h) * 4096)
#define STG_B(b, h, t)                                                \
  gload16(bS + (long)((h) * 64) * K_DIM + (t) * 32,                   \
          sBase + (b) * 16384 + 8192 + (h) * 4096)

#define LDA(m) \
  (*(const bf16x8*)(lds + bb + (wm * 64 + (m) * 16 + lr) * 64 + lg * 16))
#define LDB(n) \
  (*(const bf16x8*)(lds + bb + 8192 + (wn * 64 + (n) * 16 + lr) * 64 + lg * 16))

#define SYNC0()                                            \
  do {                                                     \
    asm volatile("s_waitcnt vmcnt(0)" ::: "memory");       \
    __builtin_amdgcn_s_barrier();                          \
    __builtin_amdgcn_sched_barrier(0);                     \
  } while (0)

  f32x4 acc[4][4] = {};
  bf16x8 afr[4], bfr[4];

  // prologue: stage tile 0 (4 issues: A0,A1,B0,B1)
  STG_A(0, 0, 0);
  STG_A(0, 1, 0);
  STG_B(0, 0, 0);
  STG_B(0, 1, 0);

#pragma unroll 1
  for (int t = 0; t < NT - 1; ++t) {
    const int b = t & 1;
    const int nb = b ^ 1;
    const int bb = b * 16384;
    SYNC0();  // tile t landed (all waves), tile t-1 reads all retired
    // issue next tile's DMA first (in flight under reads+MFMA)
    STG_A(nb, 0, t + 1);
    STG_A(nb, 1, t + 1);
    STG_B(nb, 0, t + 1);
    STG_B(nb, 1, t + 1);
#pragma unroll
    for (int m = 0; m < 4; ++m) afr[m] = LDA(m);
#pragma unroll
    for (int n = 0; n < 4; ++n) bfr[n] = LDB(n);
    __builtin_amdgcn_s_setprio(1);
#pragma unroll
    for (int m = 0; m < 4; ++m)
#pragma unroll
      for (int n = 0; n < 4; ++n)
        acc[m][n] = __builtin_amdgcn_mfma_f32_16x16x32_bf16(
            afr[m], bfr[n], acc[m][n], 0, 0, 0);
    __builtin_amdgcn_s_setprio(0);
  }
  {  // tail tile NT-1 (odd -> buf 1), no staging
    const int bb = 16384;
    SYNC0();
#pragma unroll
    for (int m = 0; m < 4; ++m) afr[m] = LDA(m);
#pragma unroll
    for (int n = 0; n < 4; ++n) bfr[n] = LDB(n);
    __builtin_amdgcn_s_setprio(1);
#pragma unroll
    for (int m = 0; m < 4; ++m)
#pragma unroll
      for (int n = 0; n < 4; ++n)
        acc[m][n] = __builtin_amdgcn_mfma_f32_16x16x32_bf16(
            afr[m], bfr[n], acc[m][n], 0, 0, 0);
    __builtin_amdgcn_s_setprio(0);
  }

#undef STG_A
#undef STG_B
#undef LDA
#undef LDB
#undef SYNC0

  // epilogue: C/D layout col = lane&15, row = (lane>>4)*4 + reg (verified)
  const float sc = *scale_p;
  const int col_base = (tn << 7) + wn * 64;
  const int row_base = (tm << 7) + wm * 64 + lg * 4;
#pragma unroll
  for (int n = 0; n < 4; ++n) {
    const int col = col_base + n * 16 + lr;
    const float bv = bias[col];
#pragma unroll
    for (int m = 0; m < 4; ++m) {
      float* cp = C + (long)(row_base + m * 16) * N_DIM + col;
#pragma unroll
      for (int j = 0; j < 4; ++j)
        __builtin_nontemporal_store(acc[m][n][j] * sc + bv, cp + (long)j * N_DIM);
    }
  }
}

// ---------------- fallback (ws too small): reg-staged 128^2 kernel --------
__global__ __launch_bounds__(256, 2) void gemm_fb_kernel(
    const float* __restrict__ Af, const bf16_t* __restrict__ Bt,
    const float* __restrict__ scale_p, const float* __restrict__ bias,
    float* __restrict__ C) {
  __shared__ bf16_t lA[128][64];
  __shared__ bf16_t lB[128][64];
  const int nwg = gridDim.x;
  int wg = blockIdx.x;
  wg = (wg & 7) * (nwg >> 3) + (wg >> 3);
  const int tm = wg & 255;
  const int tn = wg >> 8;
  const int tid = threadIdx.x;
  const int wave = tid >> 6;
  const int lane = tid & 63;
  const int lr = lane & 15;
  const int lg = lane >> 4;
  const int wm = wave >> 1;
  const int wn = wave & 1;
  const long aRow0 = (long)tm * 128;
  const long bRow0 = (long)tn * 128;
  const bf16_t* bSrc = Bt + (bRow0 + (tid >> 3)) * K_DIM + (tid & 7) * 8;
  char* ldsB = (char*)&lB[0][0] + wave * 1024;
  f32x4 acc[4][4] = {};
  for (int k0 = 0; k0 < K_DIM; k0 += 64) {
    __syncthreads();
#pragma unroll
    for (int j = 0; j < 8; ++j) {
      const int e = j * 1024 + tid * 4;
      const int row = e >> 6;
      const int col = e & 63;
      float4 v = *(const float4*)(Af + (aRow0 + row) * K_DIM + k0 + col);
      bf16x4 o;
      o[0] = (__bf16)v.x; o[1] = (__bf16)v.y; o[2] = (__bf16)v.z; o[3] = (__bf16)v.w;
      *(bf16x4*)((char*)&lA[0][0] + (size_t)e * 2) = o;
    }
#pragma unroll
    for (int i = 0; i < 4; ++i)
      gload16(bSrc + (long)i * 32 * K_DIM + k0, ldsB + i * 4096);
    __syncthreads();
#pragma unroll
    for (int kk = 0; kk < 2; ++kk) {
      bf16x8 af[4], bg[4];
#pragma unroll
      for (int m = 0; m < 4; ++m)
        af[m] = *(const bf16x8*)&lA[wm * 64 + m * 16 + lr][kk * 32 + lg * 8];
#pragma unroll
      for (int n = 0; n < 4; ++n)
        bg[n] = *(const bf16x8*)&lB[wn * 64 + n * 16 + lr][kk * 32 + lg * 8];
#pragma unroll
      for (int m = 0; m < 4; ++m)
#pragma unroll
        for (int n = 0; n < 4; ++n)
          acc[m][n] = __builtin_amdgcn_mfma_f32_16x16x32_bf16(af[m], bg[n], acc[m][n], 0, 0, 0);
    }
  }
  const float s = *scale_p;
  const int col0 = (tn << 7) + wn * 64;
  const int row0 = (tm << 7) + wm * 64 + lg * 4;
#pragma unroll
  for (int n = 0; n < 4; ++n) {
    const int col = col0 + n * 16 + lr;
    const float bv = bias[col];
#pragma unroll
    for (int m = 0; m < 4; ++m) {
      float* cp = C + (long)(row0 + m * 16) * N_DIM + col;
#pragma unroll
      for (int j = 0; j < 4; ++j)
        cp[(long)j * N_DIM] = acc[m][n][j] * s + bv;
    }
  }
}

extern "C" void kernel_launch(void* const* d_in, const int* in_sizes, int n_in,
                              void* d_out, int out_size, void* d_ws, size_t ws_size,
                              hipStream_t stream) {
  const float* x = (const float*)d_in[0];
  const int* qw = (const int*)d_in[1];  // harness pushes ints as int32
  const float* scale = (const float*)d_in[2];
  const float* bias = (const float*)d_in[3];
  float* out = (float*)d_out;

  const size_t wt_bytes = (size_t)N_DIM * K_DIM * 2;  // 8 MB
  const size_t xb_bytes = (size_t)M_DIM * K_DIM * 2;  // 64 MB
  bf16_t* wt = (bf16_t*)d_ws;
  bf16_t* xb = (bf16_t*)((char*)d_ws + wt_bytes);
  const bool apre = ws_size >= wt_bytes + xb_bytes;

  cvt_w_kernel<<<dim3((K_DIM / 64) * (N_DIM / 64)), dim3(256), 0, stream>>>(qw, wt);

  if (apre) {
    cvt_x_kernel<<<dim3(2048), dim3(256), 0, stream>>>(x, xb);
    gemm128_kernel<<<dim3((M_DIM / 128) * (N_DIM / 128)), dim3(256), 0, stream>>>(
        xb, wt, scale, bias, out);
  } else {
    gemm_fb_kernel<<<dim3((M_DIM / 128) * (N_DIM / 128)), dim3(256), 0, stream>>>(
        x, wt, scale, bias, out);
  }
}

// Round 11
// 371.989 us; speedup vs baseline: 1.0010x; 1.0010x over previous
//
#include <hip/hip_runtime.h>
#include <hip/hip_bf16.h>
#include <stdint.h>
#include <stddef.h>

typedef __bf16 bf16_t;
typedef __attribute__((ext_vector_type(8))) __bf16 bf16x8;
typedef __attribute__((ext_vector_type(4))) __bf16 bf16x4;
typedef __attribute__((ext_vector_type(4))) float f32x4;
typedef __attribute__((ext_vector_type(4))) int i32x4;

#define M_DIM 32768
#define N_DIM 4096
#define K_DIM 1024
#define NT 32  // K / 32

static __device__ __forceinline__ void gload16(const void* g, void* s) {
  __builtin_amdgcn_global_load_lds(
      (const __attribute__((address_space(1))) void*)g,
      (__attribute__((address_space(3))) void*)s,
      16, 0, 0);
}

// ---------------- x: fp32 [M][K] -> bf16 [M][K] ----------------
__global__ void cvt_x_kernel(const float* __restrict__ x, bf16_t* __restrict__ xb) {
  const long n8 = (long)M_DIM * K_DIM / 8;
  long i = (long)blockIdx.x * blockDim.x + threadIdx.x;
  const long stride = (long)gridDim.x * blockDim.x;
  for (; i < n8; i += stride) {
    const float4* p = (const float4*)(x + i * 8);
    float4 v0 = p[0];
    float4 v1 = p[1];
    bf16x8 o;
    o[0] = (__bf16)v0.x; o[1] = (__bf16)v0.y; o[2] = (__bf16)v0.z; o[3] = (__bf16)v0.w;
    o[4] = (__bf16)v1.x; o[5] = (__bf16)v1.y; o[6] = (__bf16)v1.z; o[7] = (__bf16)v1.w;
    *(bf16x8*)(xb + i * 8) = o;
  }
}

// ---------------- w: int32 [K][N] -> bf16 Wt [N][K] (exact) ----------------
__global__ void cvt_w_kernel(const int* __restrict__ qw, bf16_t* __restrict__ wt) {
  __shared__ bf16_t t[64][72];
  const int bk = blockIdx.x & 15;
  const int bn = blockIdx.x >> 4;
  const int k0 = bk * 64, n0 = bn * 64;
  const int tid = threadIdx.x;
  {
    const int kl = tid >> 2;
    const int nc = (tid & 3) * 16;
    const int* src = qw + (long)(k0 + kl) * N_DIM + n0 + nc;
#pragma unroll
    for (int c = 0; c < 4; ++c) {
      i32x4 v = *(const i32x4*)(src + c * 4);
#pragma unroll
      for (int j = 0; j < 4; ++j)
        t[nc + c * 4 + j][kl] = (bf16_t)(float)v[j];
    }
  }
  __syncthreads();
  {
    const int nl = tid >> 2;
    const int kc = (tid & 3) * 16;
    bf16_t* dst = wt + (long)(n0 + nl) * K_DIM + k0 + kc;
#pragma unroll
    for (int j = 0; j < 16; ++j) dst[j] = t[nl][kc + j];
  }
}

// ---------------- GEMM 128x128, BK=32, 4 waves, 4 blocks/CU --------------
// Round-10 structure + the missing bank-swizzle.
// MECHANISM (round-10 lesson): ds_read_b128 services 8 consecutive lanes per
// cycle (128B); conflict-free requires those 8 lanes to cover all eight 16B
// slots of the 128B bank space. 64B rows unswizzled give lanes 0-7 only the
// 2 slots (lr&1)*64 -> 4-way conflict (measured 3.35e7). Fix: LDS slot
// (row,c) holds global chunk c ^ ((row>>1)&3); lanes 0-7 then hit
// (lr&1)*64 + ((lr>>1)&3)*16 = all 8 slots.
//   staging source chunk: (lane&3) ^ ((lane>>3)&3)   [derivation: lane>>3 ==
//     ((row within issue)>>1)&3 for srow = wave*16 + lane>>2]
//   read chunk: ck = (lg ^ ((lr>>1)&3))*16  [row bits 1-2 == lr bits 1-2 in
//     every frag: wm*64, wn*64, m*16, n*16 are all 0 mod 8]
// Sync: ONE {vmcnt(0); s_barrier} per tile (RAW: own loads + barrier covers
// all waves' DMA; WAR: reads of t-1 precede the barrier). Nothing staged for
// t+1 is in flight at the wait, and 4 blocks/CU hide it.
__global__ __launch_bounds__(256, 4) void gemm128_kernel(
    const bf16_t* __restrict__ A, const bf16_t* __restrict__ Bt,
    const float* __restrict__ scale_p, const float* __restrict__ bias,
    float* __restrict__ C) {
  __shared__ __align__(16) char lds[32768];

  // XCD ownership (bijective; nwg = 8192): XCD x owns tn {4x..4x+3}; tnl
  // iterates fastest so consecutive blocks share one A-tile; all XCDs sweep
  // the same tm window concurrently (A served via LLC).
  const int xcd = blockIdx.x & 7;
  const int slot = blockIdx.x >> 3;        // 0..1023
  const int tn = (xcd << 2) | (slot & 3);  // 0..31
  const int tm = slot >> 2;                // 0..255

  const int tid = threadIdx.x;
  const int wave = tid >> 6;  // 0..3
  const int lane = tid & 63;
  const int lr = lane & 15;
  const int lg = lane >> 4;
  const int wm = wave >> 1;  // 0..1
  const int wn = wave & 1;   // 0..1

  const long aRow0 = (long)tm * 128;
  const long bRow0 = (long)tn * 128;

  // staging: issue = 4KB = 64 rows x 64B; wave w writes rows w*16..w*16+15.
  // Thread covers row srow = w*16 + lane/4; SOURCE chunk pre-swizzled.
  const int srow = wave * 16 + (lane >> 2);
  const int scol = ((lane & 3) ^ ((lane >> 3) & 3)) * 8;
  const bf16_t* aS = A + (aRow0 + srow) * K_DIM + scol;
  const bf16_t* bS = Bt + (bRow0 + srow) * K_DIM + scol;
  char* sBase = lds + wave * 1024;

  // buf b: A at b*16384 (row-major, 64B rows, 128 rows), B at b*16384+8192.
#define STG_A(b, h, t)                                                \
  gload16(aS + (long)((h) * 64) * K_DIM + (t) * 32,                   \
          sBase + (b) * 16384 + (h) * 4096)
#define STG_B(b, h, t)                                                \
  gload16(bS + (long)((h) * 64) * K_DIM + (t) * 32,                   \
          sBase + (b) * 16384 + 8192 + (h) * 4096)

  const int ck = ((lg ^ ((lr >> 1) & 3)) << 4);

#define LDA(m) \
  (*(const bf16x8*)(lds + bb + (wm * 64 + (m) * 16 + lr) * 64 + ck))
#define LDB(n) \
  (*(const bf16x8*)(lds + bb + 8192 + (wn * 64 + (n) * 16 + lr) * 64 + ck))

#define SYNC0()                                            \
  do {                                                     \
    asm volatile("s_waitcnt vmcnt(0)" ::: "memory");       \
    __builtin_amdgcn_s_barrier();                          \
    __builtin_amdgcn_sched_barrier(0);                     \
  } while (0)

  f32x4 acc[4][4] = {};
  bf16x8 afr[4], bfr[4];

  // prologue: stage tile 0 (4 issues)
  STG_A(0, 0, 0);
  STG_A(0, 1, 0);
  STG_B(0, 0, 0);
  STG_B(0, 1, 0);

#pragma unroll 1
  for (int t = 0; t < NT - 1; ++t) {
    const int b = t & 1;
    const int nb = b ^ 1;
    const int bb = b * 16384;
    SYNC0();  // tile t landed (all waves); tile t-1 reads all retired
    STG_A(nb, 0, t + 1);
    STG_A(nb, 1, t + 1);
    STG_B(nb, 0, t + 1);
    STG_B(nb, 1, t + 1);
#pragma unroll
    for (int m = 0; m < 4; ++m) afr[m] = LDA(m);
#pragma unroll
    for (int n = 0; n < 4; ++n) bfr[n] = LDB(n);
    __builtin_amdgcn_s_setprio(1);
#pragma unroll
    for (int m = 0; m < 4; ++m)
#pragma unroll
      for (int n = 0; n < 4; ++n)
        acc[m][n] = __builtin_amdgcn_mfma_f32_16x16x32_bf16(
            afr[m], bfr[n], acc[m][n], 0, 0, 0);
    __builtin_amdgcn_s_setprio(0);
  }
  {  // tail tile NT-1 (odd -> buf 1), no staging
    const int bb = 16384;
    SYNC0();
#pragma unroll
    for (int m = 0; m < 4; ++m) afr[m] = LDA(m);
#pragma unroll
    for (int n = 0; n < 4; ++n) bfr[n] = LDB(n);
    __builtin_amdgcn_s_setprio(1);
#pragma unroll
    for (int m = 0; m < 4; ++m)
#pragma unroll
      for (int n = 0; n < 4; ++n)
        acc[m][n] = __builtin_amdgcn_mfma_f32_16x16x32_bf16(
            afr[m], bfr[n], acc[m][n], 0, 0, 0);
    __builtin_amdgcn_s_setprio(0);
  }

#undef STG_A
#undef STG_B
#undef LDA
#undef LDB
#undef SYNC0

  // epilogue: C/D layout col = lane&15, row = (lane>>4)*4 + reg (verified)
  const float sc = *scale_p;
  const int col_base = (tn << 7) + wn * 64;
  const int row_base = (tm << 7) + wm * 64 + lg * 4;
#pragma unroll
  for (int n = 0; n < 4; ++n) {
    const int col = col_base + n * 16 + lr;
    const float bv = bias[col];
#pragma unroll
    for (int m = 0; m < 4; ++m) {
      float* cp = C + (long)(row_base + m * 16) * N_DIM + col;
#pragma unroll
      for (int j = 0; j < 4; ++j)
        __builtin_nontemporal_store(acc[m][n][j] * sc + bv, cp + (long)j * N_DIM);
    }
  }
}

// ---------------- fallback (ws too small): reg-staged 128^2 kernel --------
__global__ __launch_bounds__(256, 2) void gemm_fb_kernel(
    const float* __restrict__ Af, const bf16_t* __restrict__ Bt,
    const float* __restrict__ scale_p, const float* __restrict__ bias,
    float* __restrict__ C) {
  __shared__ bf16_t lA[128][64];
  __shared__ bf16_t lB[128][64];
  const int nwg = gridDim.x;
  int wg = blockIdx.x;
  wg = (wg & 7) * (nwg >> 3) + (wg >> 3);
  const int tm = wg & 255;
  const int tn = wg >> 8;
  const int tid = threadIdx.x;
  const int wave = tid >> 6;
  const int lane = tid & 63;
  const int lr = lane & 15;
  const int lg = lane >> 4;
  const int wm = wave >> 1;
  const int wn = wave & 1;
  const long aRow0 = (long)tm * 128;
  const long bRow0 = (long)tn * 128;
  const bf16_t* bSrc = Bt + (bRow0 + (tid >> 3)) * K_DIM + (tid & 7) * 8;
  char* ldsB = (char*)&lB[0][0] + wave * 1024;
  f32x4 acc[4][4] = {};
  for (int k0 = 0; k0 < K_DIM; k0 += 64) {
    __syncthreads();
#pragma unroll
    for (int j = 0; j < 8; ++j) {
      const int e = j * 1024 + tid * 4;
      const int row = e >> 6;
      const int col = e & 63;
      float4 v = *(const float4*)(Af + (aRow0 + row) * K_DIM + k0 + col);
      bf16x4 o;
      o[0] = (__bf16)v.x; o[1] = (__bf16)v.y; o[2] = (__bf16)v.z; o[3] = (__bf16)v.w;
      *(bf16x4*)((char*)&lA[0][0] + (size_t)e * 2) = o;
    }
#pragma unroll
    for (int i = 0; i < 4; ++i)
      gload16(bSrc + (long)i * 32 * K_DIM + k0, ldsB + i * 4096);
    __syncthreads();
#pragma unroll
    for (int kk = 0; kk < 2; ++kk) {
      bf16x8 af[4], bg[4];
#pragma unroll
      for (int m = 0; m < 4; ++m)
        af[m] = *(const bf16x8*)&lA[wm * 64 + m * 16 + lr][kk * 32 + lg * 8];
#pragma unroll
      for (int n = 0; n < 4; ++n)
        bg[n] = *(const bf16x8*)&lB[wn * 64 + n * 16 + lr][kk * 32 + lg * 8];
#pragma unroll
      for (int m = 0; m < 4; ++m)
#pragma unroll
        for (int n = 0; n < 4; ++n)
          acc[m][n] = __builtin_amdgcn_mfma_f32_16x16x32_bf16(af[m], bg[n], acc[m][n], 0, 0, 0);
    }
  }
  const float s = *scale_p;
  const int col0 = (tn << 7) + wn * 64;
  const int row0 = (tm << 7) + wm * 64 + lg * 4;
#pragma unroll
  for (int n = 0; n < 4; ++n) {
    const int col = col0 + n * 16 + lr;
    const float bv = bias[col];
#pragma unroll
    for (int m = 0; m < 4; ++m) {
      float* cp = C + (long)(row0 + m * 16) * N_DIM + col;
#pragma unroll
      for (int j = 0; j < 4; ++j)
        cp[(long)j * N_DIM] = acc[m][n][j] * s + bv;
    }
  }
}

extern "C" void kernel_launch(void* const* d_in, const int* in_sizes, int n_in,
                              void* d_out, int out_size, void* d_ws, size_t ws_size,
                              hipStream_t stream) {
  const float* x = (const float*)d_in[0];
  const int* qw = (const int*)d_in[1];  // harness pushes ints as int32
  const float* scale = (const float*)d_in[2];
  const float* bias = (const float*)d_in[3];
  float* out = (float*)d_out;

  const size_t wt_bytes = (size_t)N_DIM * K_DIM * 2;  // 8 MB
  const size_t xb_bytes = (size_t)M_DIM * K_DIM * 2;  // 64 MB
  bf16_t* wt = (bf16_t*)d_ws;
  bf16_t* xb = (bf16_t*)((char*)d_ws + wt_bytes);
  const bool apre = ws_size >= wt_bytes + xb_bytes;

  cvt_w_kernel<<<dim3((K_DIM / 64) * (N_DIM / 64)), dim3(256), 0, stream>>>(qw, wt);

  if (apre) {
    cvt_x_kernel<<<dim3(2048), dim3(256), 0, stream>>>(x, xb);
    gemm128_kernel<<<dim3((M_DIM / 128) * (N_DIM / 128)), dim3(256), 0, stream>>>(
        xb, wt, scale, bias, out);
  } else {
    gemm_fb_kernel<<<dim3((M_DIM / 128) * (N_DIM / 128)), dim3(256), 0, stream>>>(
        x, wt, scale, bias, out);
  }
}